// Round 1
// 554.451 us; speedup vs baseline: 1.2885x; 1.2885x over previous
//
#include <hip/hip_runtime.h>
#include <stdint.h>

#define N_NODES 128
#define T_DIM   4096
#define E_EDGES 72
#define IN_DIM  128
#define OUT_DIM 128
#define NRULE   3
#define TT      64          // T rows per block
#define MAT_ELEMS 16384     // 128*128 bf16 elems per weight matrix (32 KB)

typedef float  f32x4 __attribute__((ext_vector_type(4)));
typedef short  s16x8 __attribute__((ext_vector_type(8)));

static __device__ __forceinline__ unsigned short f2bf(float f) {
    union { float f; unsigned int u; } v; v.f = f;
    unsigned int r = (v.u + 0x7FFFu + ((v.u >> 16) & 1u)) >> 16;  // RNE
    return (unsigned short)r;
}

// pack two f32 -> two bf16 (RNE) in one instruction
static __device__ __forceinline__ unsigned cvt_pk_bf16(float lo, float hi) {
    unsigned r;
    asm("v_cvt_pk_bf16_f32 %0, %1, %2" : "=v"(r) : "v"(lo), "v"(hi));
    return r;
}

// Convert weight[8][3][128][128] and loop_weight[128][128] (fp32) into bf16
// B-fragment order: wsB[mat][kstep][ntile][lane][j], mat 0..23 = et*3+r, 24 = loop.
// Fragment element j of lane L is B[k = kstep*32 + (L>>4)*8 + j][n = ntile*16 + (L&15)].
__global__ void conv_weights(const float* __restrict__ weight,
                             const float* __restrict__ loop_w,
                             unsigned short* __restrict__ wsB) {
    int g = blockIdx.x * blockDim.x + threadIdx.x;   // 25*2048 threads, 8 elems each
    if (g >= 25 * 2048) return;
    int mat  = g >> 11;
    int rem  = g & 2047;
    int kstep = rem >> 9;
    int nt    = (rem >> 6) & 7;
    int lane  = rem & 63;
    int quad = lane >> 4, l16 = lane & 15;
    const float* src = (mat < 24) ? (weight + (size_t)mat * IN_DIM * OUT_DIM) : loop_w;
    int col = nt * 16 + l16;
    int k0  = kstep * 32 + quad * 8;
    unsigned short tmp[8];
#pragma unroll
    for (int j = 0; j < 8; ++j)
        tmp[j] = f2bf(src[(size_t)(k0 + j) * OUT_DIM + col]);
    *(uint4*)(wsB + (size_t)g * 8) = *(const uint4*)tmp;   // 16B coalesced
}

__launch_bounds__(256)
__global__ void rgcn_main(const float* __restrict__ feat,
                          const float* __restrict__ tvg,
                          const float* __restrict__ h_bias,
                          const int*   __restrict__ src_idx,
                          const int*   __restrict__ dst_idx,
                          const int*   __restrict__ etypes,
                          const unsigned short* __restrict__ wsB,
                          float* __restrict__ out) {
    // double-buffered B matrix (one full 128x128 bf16 weight mat per buffer)
    __shared__ unsigned short sB[2 * MAT_ELEMS];          // 64 KB
    __shared__ int sSrc[E_EDGES], sDst[E_EDGES], sEt[E_EDGES];
    __shared__ int sJobSrc[E_EDGES], sJobMat[E_EDGES], sJobE[E_EDGES];
    __shared__ int sNJobs;

    const int tid  = threadIdx.x;
    const int n    = blockIdx.x & (N_NODES - 1);
    const int t0   = (blockIdx.x >> 7) * TT;
    const int wv   = __builtin_amdgcn_readfirstlane(tid >> 6);  // wave id (uniform)
    const int lane = tid & 63;
    const int quad = lane >> 4, l16 = lane & 15;

    // async stage of one 32 KB weight matrix into sB[which]; each wave moves 8 KB
    auto stageB = [&](int mat, int which) {
        const unsigned short* g = wsB + (size_t)mat * MAT_ELEMS + wv * 4096 + lane * 8;
        unsigned short* l = sB + which * MAT_ELEMS + wv * 4096;
#pragma unroll
        for (int i = 0; i < 8; ++i)
            __builtin_amdgcn_global_load_lds(
                (const __attribute__((address_space(1))) void*)(g + i * 512),
                (__attribute__((address_space(3))) void*)(l + i * 512), 16, 0, 0);
    };

    // ---- prologue: start staging self-loop matrix (mat 24) into buf 0 ----
    stageB(24, 0);

    if (tid < E_EDGES) {
        sSrc[tid] = src_idx[tid];
        sDst[tid] = dst_idx[tid];
        sEt[tid]  = etypes[tid];
    }
    __syncthreads();                       // edge arrays ready; B stage drained too
    if (tid == 0) {                        // compact incident-edge job list (LDS only)
        int m = 0;
        for (int e = 0; e < E_EDGES; ++e)
            if (sDst[e] == n) { sJobSrc[m] = sSrc[e]; sJobMat[m] = sEt[e] * 3; sJobE[m] = e; ++m; }
        sNJobs = m;
    }
    __syncthreads();
    const int nJobs  = sNJobs;
    const int nSteps = 1 + NRULE * nJobs;  // step 0 = self, then 3 rule-steps per edge

    f32x4 acc[8];
#pragma unroll
    for (int i = 0; i < 8; ++i) acc[i] = f32x4{0.f, 0.f, 0.f, 0.f};

    // per-lane A row: this lane's MFMA A-fragment row is (wv*16 + l16)
    const size_t arow = (size_t)(t0 + wv * 16 + l16);

    float4 afa[4], afb[4];                 // current job's A fragments, f32 (32 VGPRs)
    int buf = 0;
    int j = 0, r = -1;                     // (j,r) describe step s for s>=1

    for (int s = 0; s < nSteps; ++s) {
        const bool isSelf = (s == 0);

        // ---- 1) A-fragment + tv loads for this step (issued BEFORE the stage
        //         so consuming them doesn't drain the in-flight global_load_lds) ----
        if (isSelf || r == 0) {            // job start: load 16 rows x 32B of feat (f32)
            int srcn = isSelf ? n : sJobSrc[j];
            const float* ab = feat + ((size_t)srcn * T_DIM + arow) * IN_DIM + quad * 8;
#pragma unroll
            for (int k = 0; k < 4; ++k) {
                afa[k] = *(const float4*)(ab + k * 32);
                afb[k] = *(const float4*)(ab + k * 32 + 4);
            }
        }
        float tscale = 1.0f;
        if (!isSelf)
            tscale = tvg[((size_t)sJobE[j] * T_DIM + arow) * NRULE + r];

        __builtin_amdgcn_sched_barrier(0); // pin: af/tv issue before stage issue

        // ---- 2) async stage of next step's B matrix into the other buffer ----
        if (s + 1 < nSteps) {
            int jn, rn;
            if (s == 0)       { jn = 0;     rn = 0; }
            else if (r == 2)  { jn = j + 1; rn = 0; }
            else              { jn = j;     rn = r + 1; }
            stageB(sJobMat[jn] + rn, buf ^ 1);
        }

        // ---- 3) compute: acc += bf16(tv * A) @ B   (A' folding, direct accumulate) ----
        const unsigned short* bb = sB + buf * MAT_ELEMS + lane * 8;
#pragma unroll
        for (int k = 0; k < 4; ++k) {
            union { unsigned u[4]; s16x8 v; } A;
            if (isSelf) {
                A.u[0] = cvt_pk_bf16(afa[k].x, afa[k].y);
                A.u[1] = cvt_pk_bf16(afa[k].z, afa[k].w);
                A.u[2] = cvt_pk_bf16(afb[k].x, afb[k].y);
                A.u[3] = cvt_pk_bf16(afb[k].z, afb[k].w);
            } else {
                A.u[0] = cvt_pk_bf16(tscale * afa[k].x, tscale * afa[k].y);
                A.u[1] = cvt_pk_bf16(tscale * afa[k].z, tscale * afa[k].w);
                A.u[2] = cvt_pk_bf16(tscale * afb[k].x, tscale * afb[k].y);
                A.u[3] = cvt_pk_bf16(tscale * afb[k].z, tscale * afb[k].w);
            }
#pragma unroll
            for (int nt = 0; nt < 8; ++nt) {
                s16x8 b = *(const s16x8*)(bb + k * 4096 + nt * 512);
                acc[nt] = __builtin_amdgcn_mfma_f32_16x16x32_bf16(A.v, b, acc[nt], 0, 0, 0);
            }
        }

        // ---- 4) drain stage + barrier, flip buffers, advance (j,r) ----
        __syncthreads();
        buf ^= 1;
        if (s == 0)      { j = 0; r = 0; }
        else if (r == 2) { ++j;   r = 0; }
        else             { ++r; }
    }

    // ---- epilogue: bias + nontemporal store (full overwrite) ----
#pragma unroll
    for (int nt = 0; nt < 8; ++nt) {
        float bias = h_bias[nt * 16 + l16];
#pragma unroll
        for (int reg = 0; reg < 4; ++reg) {
            int row = t0 + wv * 16 + quad * 4 + reg;
            float v = acc[nt][reg] + bias;
            __builtin_nontemporal_store(v, &out[((size_t)n * T_DIM + row) * OUT_DIM + nt * 16 + l16]);
        }
    }
}

extern "C" void kernel_launch(void* const* d_in, const int* in_sizes, int n_in,
                              void* d_out, int out_size, void* d_ws, size_t ws_size,
                              hipStream_t stream) {
    const float* feat   = (const float*)d_in[0];
    const float* tv     = (const float*)d_in[1];
    const float* weight = (const float*)d_in[2];
    const float* loop_w = (const float*)d_in[3];
    const float* h_bias = (const float*)d_in[4];
    const int*   src    = (const int*)d_in[5];
    const int*   dst    = (const int*)d_in[6];
    const int*   et     = (const int*)d_in[7];
    float* out = (float*)d_out;

    unsigned short* wsB = (unsigned short*)d_ws;   // 25 * 16384 bf16 = 819200 B

    conv_weights<<<(25 * 2048 + 255) / 256, 256, 0, stream>>>(weight, loop_w, wsB);

    dim3 grid(N_NODES * (T_DIM / TT));             // 8192 blocks
    rgcn_main<<<grid, 256, 0, stream>>>(feat, tv, h_bias, src, dst, et, wsB, out);
}